// Round 4
// baseline (518.443 us; speedup 1.0000x reference)
//
#include <hip/hip_runtime.h>
#include <math.h>

typedef __attribute__((ext_vector_type(8))) short short8;
typedef __attribute__((ext_vector_type(4))) float f32x4;

__device__ __forceinline__ unsigned short f2bf(float x) {
    unsigned u = __float_as_uint(x);
    u += 0x7FFFu + ((u >> 16) & 1u);   // round-to-nearest-even
    return (unsigned short)(u >> 16);
}

// Workspace layout (bytes)
#define A1P_OFF   131072
#define VEHB_OFF  196608
#define PART_OFF  720896
#define CNT_OFF   4915200

// Kernel 1: W2p fragments, A1p fragments, vehb = obs@W1[:15]+b1 per batch, zero counters.
__global__ __launch_bounds__(256) void prep_kernel(const float* __restrict__ W2,
                                                   const float* __restrict__ W1,
                                                   const float* __restrict__ obs,
                                                   const float* __restrict__ b1,
                                                   unsigned short* __restrict__ W2p,
                                                   unsigned short* __restrict__ A1p,
                                                   float* __restrict__ vehb,
                                                   unsigned* __restrict__ cnt) {
    const int t = threadIdx.x;
    const int blk = blockIdx.x;
    if (blk < 512) {
        float a = b1[t];
#pragma unroll
        for (int i = 0; i < 15; ++i) a = fmaf(obs[blk * 15 + i], W1[i * 256 + t], a);
        vehb[blk * 256 + t] = a;
    } else {
        int aux = blk - 512;
        if (aux < 32) {
            // W2p: frag f=(kt*16+ct)*64+l, elem j = W2[kt*32+(l>>4)*8+j][ct*16+(l&15)]
            int f = aux * 256 + t;
            int l = f & 63, ct = (f >> 6) & 15, kt = f >> 10;
            int col = ct * 16 + (l & 15);
            int krow = kt * 32 + ((l >> 4) * 8);
            short8 v;
#pragma unroll
            for (int j = 0; j < 8; ++j) v[j] = (short)f2bf(W2[(krow + j) * 256 + col]);
            *reinterpret_cast<short8*>(W2p + (size_t)f * 8) = v;
        } else if (aux < 36) {
            // A1p: W1obst^T A-fragments (M=j, K=32, only k<4 nonzero)
            int f = (aux - 32) * 256 + t;   // 0..1023
            int l = f & 63, jt = f >> 6;
            int j = jt * 16 + (l & 15);
            short8 v;
#pragma unroll
            for (int jj = 0; jj < 8; ++jj) {
                int k = (l >> 4) * 8 + jj;
                v[jj] = (k < 4) ? (short)f2bf(W1[(15 + k) * 256 + j]) : (short)0;
            }
            *reinterpret_cast<short8*>(A1p + (size_t)f * 8) = v;
        } else {
            cnt[t] = 0u;
            cnt[256 + t] = 0u;
        }
    }
}

// Kernel 2: per (batch, row-octant). MFMA layer1 -> LDS -> MFMA layer2 -> masked pool
// -> deterministic partial store; last-arriving block of each batch computes the head.
__global__ __launch_bounds__(256, 4) void actor_kernel(
    const float* __restrict__ obst, const float* __restrict__ b2,
    const unsigned short* __restrict__ W2p, const unsigned short* __restrict__ A1p,
    const float* __restrict__ vehb, float* __restrict__ partial,
    unsigned* __restrict__ cnt,
    const float* __restrict__ eps, const float* __restrict__ muW,
    const float* __restrict__ mub, const float* __restrict__ lsW,
    const float* __restrict__ lsb, float* __restrict__ out)
{
    __shared__ __align__(16) short sA[32 * 256];   // h1 bf16 [n][j], 512-B rows, XOR-swizzled
    __shared__ float sRed[4][4];
    __shared__ int sFlag;

    const int bq = blockIdx.x;
    const int b = bq >> 3;
    const int q = bq & 7;
    const int t = threadIdx.x;
    const int l = t & 63;
    const int w = t >> 6;

    // ---- layer-1 B-fragments from obstacles (K=4 in low k-slots) ----
    const float* ob = obst + b * 1280 + q * 32;
    short8 bf1[2];
#pragma unroll
    for (int nt = 0; nt < 2; ++nt) {
        short8 v = {0, 0, 0, 0, 0, 0, 0, 0};
        if (l < 16) {
#pragma unroll
            for (int jj = 0; jj < 4; ++jj)
                v[jj] = (short)f2bf(ob[jj * 256 + nt * 16 + l]);
        }
        bf1[nt] = v;
    }
    short8 a1[4];
#pragma unroll
    for (int ji = 0; ji < 4; ++ji)
        a1[ji] = *reinterpret_cast<const short8*>(A1p + (size_t)(((w * 4 + ji) * 64 + l) * 8));

    // ---- layer 1: MFMA -> +bias -> relu -> bf16 -> swizzled LDS ----
#pragma unroll
    for (int ji = 0; ji < 4; ++ji) {
        int jt = w * 4 + ji;
        f32x4 d0 = (f32x4){0.f, 0.f, 0.f, 0.f};
        f32x4 d1 = (f32x4){0.f, 0.f, 0.f, 0.f};
        d0 = __builtin_amdgcn_mfma_f32_16x16x32_bf16(a1[ji], bf1[0], d0, 0, 0, 0);
        d1 = __builtin_amdgcn_mfma_f32_16x16x32_bf16(a1[ji], bf1[1], d1, 0, 0, 0);
        f32x4 bias = *reinterpret_cast<const f32x4*>(&vehb[b * 256 + jt * 16 + ((l >> 4) * 4)]);
        unsigned jbyte = (unsigned)(jt * 32 + ((l >> 4) * 8));
#pragma unroll
        for (int nt = 0; nt < 2; ++nt) {
            f32x4 d = (nt == 0) ? d0 : d1;
            int n = nt * 16 + (l & 15);
            unsigned p0 = (unsigned)f2bf(fmaxf(d[0] + bias[0], 0.f));
            unsigned p1 = (unsigned)f2bf(fmaxf(d[1] + bias[1], 0.f));
            unsigned p2 = (unsigned)f2bf(fmaxf(d[2] + bias[2], 0.f));
            unsigned p3 = (unsigned)f2bf(fmaxf(d[3] + bias[3], 0.f));
            uint2 u;
            u.x = p0 | (p1 << 16);
            u.y = p2 | (p3 << 16);
            unsigned off = (unsigned)(n * 512) + (jbyte ^ ((unsigned)((n & 7) << 4)));
            *reinterpret_cast<uint2*>((char*)sA + off) = u;
        }
    }
    __syncthreads();

    // ---- layer 2: full-K MFMA ----
    f32x4 acc[2][4];
#pragma unroll
    for (int m = 0; m < 2; ++m)
#pragma unroll
        for (int c = 0; c < 4; ++c) acc[m][c] = (f32x4){0.f, 0.f, 0.f, 0.f};

#pragma unroll
    for (int kt = 0; kt < 8; ++kt) {
        short8 bfr[4];
#pragma unroll
        for (int c = 0; c < 4; ++c)
            bfr[c] = *reinterpret_cast<const short8*>(
                W2p + (size_t)(((kt * 16 + w * 4 + c) * 64 + l) * 8));
#pragma unroll
        for (int m = 0; m < 2; ++m) {
            int n = m * 16 + (l & 15);
            unsigned off = (unsigned)(n * 512) +
                           (((unsigned)(kt * 64 + ((l >> 4) * 16))) ^ ((unsigned)((n & 7) << 4)));
            short8 afr = *reinterpret_cast<const short8*>((const char*)sA + off);
#pragma unroll
            for (int c = 0; c < 4; ++c)
                acc[m][c] = __builtin_amdgcn_mfma_f32_16x16x32_bf16(afr, bfr[c], acc[m][c], 0, 0, 0);
        }
    }

    // ---- masked pool of 32 rows -> deterministic partial store ----
    const float* maskp = obst + b * 1280 + 1024 + q * 32;
#pragma unroll
    for (int c = 0; c < 4; ++c) {
        int col = w * 64 + c * 16 + (l & 15);
        float bb = b2[col];
        float p = 0.f;
#pragma unroll
        for (int m = 0; m < 2; ++m) {
            int r0 = m * 16 + ((l >> 4) * 4);
            float4 M = *reinterpret_cast<const float4*>(maskp + r0);
            f32x4 v = acc[m][c];
            p = fmaf(M.x, fmaxf(v[0] + bb, 0.f), p);
            p = fmaf(M.y, fmaxf(v[1] + bb, 0.f), p);
            p = fmaf(M.z, fmaxf(v[2] + bb, 0.f), p);
            p = fmaf(M.w, fmaxf(v[3] + bb, 0.f), p);
        }
        p += __shfl_xor(p, 16);
        p += __shfl_xor(p, 32);
        if (l < 16)
            __hip_atomic_store(&partial[bq * 256 + col], p,
                               __ATOMIC_RELAXED, __HIP_MEMORY_SCOPE_AGENT);
    }
    __threadfence();
    __syncthreads();
    if (t == 0) {
        unsigned old = __hip_atomic_fetch_add(&cnt[b], 1u,
                                              __ATOMIC_ACQ_REL, __HIP_MEMORY_SCOPE_AGENT);
        sFlag = (old == 7u) ? 1 : 0;
    }
    __syncthreads();

    // ---- last arriver computes the Gaussian head for this batch ----
    if (sFlag) {
        __threadfence();
        float ps = 0.f;
#pragma unroll
        for (int qq = 0; qq < 8; ++qq)
            ps += __hip_atomic_load(&partial[(b * 8 + qq) * 256 + t],
                                    __ATOMIC_RELAXED, __HIP_MEMORY_SCOPE_AGENT);
        float m0 = ps * muW[t * 2 + 0], m1 = ps * muW[t * 2 + 1];
        float s0 = ps * lsW[t * 2 + 0], s1 = ps * lsW[t * 2 + 1];
#pragma unroll
        for (int off = 32; off > 0; off >>= 1) {
            m0 += __shfl_xor(m0, off);
            m1 += __shfl_xor(m1, off);
            s0 += __shfl_xor(s0, off);
            s1 += __shfl_xor(s1, off);
        }
        if (l == 0) { sRed[w][0] = m0; sRed[w][1] = m1; sRed[w][2] = s0; sRed[w][3] = s1; }
        __syncthreads();
        if (t == 0) {
            float M0 = sRed[0][0] + sRed[1][0] + sRed[2][0] + sRed[3][0];
            float M1 = sRed[0][1] + sRed[1][1] + sRed[2][1] + sRed[3][1];
            float S0 = sRed[0][2] + sRed[1][2] + sRed[2][2] + sRed[3][2];
            float S1 = sRed[0][3] + sRed[1][3] + sRed[2][3] + sRed[3][3];
            float mu0 = M0 + mub[0], mu1 = M1 + mub[1];
            float ls0 = fminf(fmaxf(S0 + lsb[0], -20.f), 2.f);
            float ls1 = fminf(fmaxf(S1 + lsb[1], -20.f), 2.f);
            float e0 = eps[b * 2 + 0], e1 = eps[b * 2 + 1];
            float a0 = fmaf(expf(ls0), e0, mu0);
            float a1 = fmaf(expf(ls1), e1, mu1);
            float logp = -0.5f * (e0 * e0 + e1 * e1) - (ls0 + ls1) - 1.8378770664093453f;
            float x0 = -2.f * a0, x1 = -2.f * a1;
            float sp0 = fmaxf(x0, 0.f) + log1pf(expf(-fabsf(x0)));
            float sp1 = fmaxf(x1, 0.f) + log1pf(expf(-fabsf(x1)));
            logp -= 2.f * (0.6931471805599453f - a0 - sp0);
            logp -= 2.f * (0.6931471805599453f - a1 - sp1);
            out[b * 2 + 0] = tanhf(a0);
            out[b * 2 + 1] = tanhf(a1);
            out[1024 + b] = logp;
        }
    }
}

extern "C" void kernel_launch(void* const* d_in, const int* in_sizes, int n_in,
                              void* d_out, int out_size, void* d_ws, size_t ws_size,
                              hipStream_t stream) {
    const float* obs  = (const float*)d_in[0];
    const float* obst = (const float*)d_in[1];
    const float* eps  = (const float*)d_in[2];
    const float* W1   = (const float*)d_in[3];
    const float* b1   = (const float*)d_in[4];
    const float* W2   = (const float*)d_in[5];
    const float* b2   = (const float*)d_in[6];
    const float* muW  = (const float*)d_in[7];
    const float* mub  = (const float*)d_in[8];
    const float* lsW  = (const float*)d_in[9];
    const float* lsb  = (const float*)d_in[10];
    float* out = (float*)d_out;

    char* ws = (char*)d_ws;
    unsigned short* W2p = (unsigned short*)ws;
    unsigned short* A1p = (unsigned short*)(ws + A1P_OFF);
    float* vehb         = (float*)(ws + VEHB_OFF);
    float* partial      = (float*)(ws + PART_OFF);
    unsigned* cnt       = (unsigned*)(ws + CNT_OFF);

    prep_kernel<<<549, 256, 0, stream>>>(W2, W1, obs, b1, W2p, A1p, vehb, cnt);
    actor_kernel<<<4096, 256, 0, stream>>>(obst, b2, W2p, A1p, vehb, partial, cnt,
                                           eps, muW, mub, lsW, lsb, out);
}

// Round 5
// 45.329 us; speedup vs baseline: 11.4372x; 11.4372x over previous
//
#include <hip/hip_runtime.h>
#include <math.h>

typedef __attribute__((ext_vector_type(8))) short short8;
typedef __attribute__((ext_vector_type(4))) float f32x4;

__device__ __forceinline__ unsigned short f2bf(float x) {
    unsigned u = __float_as_uint(x);
    u += 0x7FFFu + ((u >> 16) & 1u);   // round-to-nearest-even
    return (unsigned short)(u >> 16);
}

// Workspace layout (bytes)
#define A1P_OFF   131072
#define ACCV_OFF  147456

// Kernel 1 (37 blocks): W2p fragments, A1p fragments, zero accv[512*4].
__global__ __launch_bounds__(256) void prep_kernel(const float* __restrict__ W2,
                                                   const float* __restrict__ W1,
                                                   unsigned short* __restrict__ W2p,
                                                   unsigned short* __restrict__ A1p,
                                                   float* __restrict__ accv) {
    const int t = threadIdx.x;
    const int blk = blockIdx.x;
    if (blk < 32) {
        // W2p: frag f=(kt*16+ct)*64+l, elem j = W2[kt*32+(l>>4)*8+j][ct*16+(l&15)]
        int f = blk * 256 + t;
        int l = f & 63, ct = (f >> 6) & 15, kt = f >> 10;
        int col = ct * 16 + (l & 15);
        int krow = kt * 32 + ((l >> 4) * 8);
        short8 v;
#pragma unroll
        for (int j = 0; j < 8; ++j) v[j] = (short)f2bf(W2[(krow + j) * 256 + col]);
        *reinterpret_cast<short8*>(W2p + (size_t)f * 8) = v;
    } else if (blk < 36) {
        // A1p: W1obst^T A-fragments (M=j, K=32, only k<4 nonzero)
        int f = (blk - 32) * 256 + t;   // 0..1023
        int l = f & 63, jt = f >> 6;
        int j = jt * 16 + (l & 15);
        short8 v;
#pragma unroll
        for (int jj = 0; jj < 8; ++jj) {
            int k = (l >> 4) * 8 + jj;
            v[jj] = (k < 4) ? (short)f2bf(W1[(15 + k) * 256 + j]) : (short)0;
        }
        *reinterpret_cast<short8*>(A1p + (size_t)f * 8) = v;
    } else {
#pragma unroll
        for (int i = 0; i < 8; ++i) accv[i * 256 + t] = 0.f;
    }
}

// Kernel 2 (2048 blocks): per (batch, row-quarter: 64 rows). MFMA layer1 -> LDS (128-B rows)
// -> MFMA layer2 -> masked pool dotted with muW/lsW -> 4 atomicAdds into accv[b][4].
__global__ __launch_bounds__(256, 3) void actor_kernel(
    const float* __restrict__ obs,  const float* __restrict__ obst,
    const float* __restrict__ W1,   const float* __restrict__ b1,
    const float* __restrict__ b2,   const unsigned short* __restrict__ W2p,
    const unsigned short* __restrict__ A1p,
    const float* __restrict__ muW,  const float* __restrict__ lsW,
    float* __restrict__ accv)
{
    // h1 bf16, 4 pages x (64 rows x 64 k), rows of 128 B, XOR-swizzled within row
    __shared__ __align__(16) short sA[4 * 64 * 64];
    __shared__ float sVeh[256];

    const int bq = blockIdx.x;
    const int b = bq >> 2;
    const int q = bq & 3;            // rows [q*64, q*64+64)
    const int t = threadIdx.x;
    const int l = t & 63;
    const int w = t >> 6;
    const int g = l >> 4;
    const int ln = l & 15;

    // per-batch bias vector veh@W1[:15]+b1 (recomputed per block; 15 fma/thread)
    {
        float a = b1[t];
#pragma unroll
        for (int i = 0; i < 15; ++i) a = fmaf(obs[b * 15 + i], W1[i * 256 + t], a);
        sVeh[t] = a;
    }

    // layer-1 B-fragments from obstacles (K=4 in low k-slots), 4 n-tiles
    const float* ob = obst + b * 1280 + q * 64;
    short8 bf1[4];
#pragma unroll
    for (int nt = 0; nt < 4; ++nt) {
        short8 v = {0, 0, 0, 0, 0, 0, 0, 0};
        if (l < 16) {
#pragma unroll
            for (int jj = 0; jj < 4; ++jj)
                v[jj] = (short)f2bf(ob[jj * 256 + nt * 16 + l]);
        }
        bf1[nt] = v;
    }
    short8 a1[4];
#pragma unroll
    for (int ji = 0; ji < 4; ++ji)
        a1[ji] = *reinterpret_cast<const short8*>(A1p + (size_t)(((w * 4 + ji) * 64 + l) * 8));

    __syncthreads();   // sVeh ready

    // layer 1: D[j][n] -> +bias -> relu -> bf16 -> LDS
#pragma unroll
    for (int ji = 0; ji < 4; ++ji) {
        int jt = w * 4 + ji;
        f32x4 bias = *reinterpret_cast<const f32x4*>(&sVeh[jt * 16 + g * 4]);
        int j0 = jt * 16 + g * 4;
        unsigned jbyte = (unsigned)(((j0 & 63) * 2));
        unsigned page = (unsigned)(j0 >> 6) * 8192;
#pragma unroll
        for (int nt = 0; nt < 4; ++nt) {
            f32x4 d = (f32x4){0.f, 0.f, 0.f, 0.f};
            d = __builtin_amdgcn_mfma_f32_16x16x32_bf16(a1[ji], bf1[nt], d, 0, 0, 0);
            int n = nt * 16 + ln;
            unsigned p0 = (unsigned)f2bf(fmaxf(d[0] + bias[0], 0.f));
            unsigned p1 = (unsigned)f2bf(fmaxf(d[1] + bias[1], 0.f));
            unsigned p2 = (unsigned)f2bf(fmaxf(d[2] + bias[2], 0.f));
            unsigned p3 = (unsigned)f2bf(fmaxf(d[3] + bias[3], 0.f));
            uint2 u;
            u.x = p0 | (p1 << 16);
            u.y = p2 | (p3 << 16);
            unsigned off = page + (unsigned)(n * 128) + (jbyte ^ ((unsigned)((n & 7) << 4)));
            *reinterpret_cast<uint2*>((char*)sA + off) = u;
        }
    }
    __syncthreads();   // h1 ready

    // layer 2: full-K MFMA; B-frags from W2p (L2-hot), A-frags from LDS
    f32x4 acc[4][4];
#pragma unroll
    for (int m = 0; m < 4; ++m)
#pragma unroll
        for (int c = 0; c < 4; ++c) acc[m][c] = (f32x4){0.f, 0.f, 0.f, 0.f};

#pragma unroll
    for (int kt = 0; kt < 8; ++kt) {
        short8 bfr[4];
#pragma unroll
        for (int c = 0; c < 4; ++c)
            bfr[c] = *reinterpret_cast<const short8*>(
                W2p + (size_t)(((kt * 16 + w * 4 + c) * 64 + l) * 8));
        unsigned page = (unsigned)(kt >> 1) * 8192;
        unsigned kbyte = ((unsigned)((kt & 1) * 64 + g * 16));
#pragma unroll
        for (int m = 0; m < 4; ++m) {
            int n = m * 16 + ln;
            unsigned off = page + (unsigned)(n * 128) + (kbyte ^ ((unsigned)((n & 7) << 4)));
            short8 afr = *reinterpret_cast<const short8*>((const char*)sA + off);
#pragma unroll
            for (int c = 0; c < 4; ++c)
                acc[m][c] = __builtin_amdgcn_mfma_f32_16x16x32_bf16(afr, bfr[c], acc[m][c], 0, 0, 0);
        }
    }

    // masked pool of 64 rows, fused dot with muW/lsW -> 4 scalars per wave
    const float* maskp = obst + b * 1280 + 1024 + q * 64;
    float m0 = 0.f, m1 = 0.f, s0 = 0.f, s1 = 0.f;
#pragma unroll
    for (int c = 0; c < 4; ++c) {
        int col = w * 64 + c * 16 + ln;
        float bb = b2[col];
        float p = 0.f;
#pragma unroll
        for (int m = 0; m < 4; ++m) {
            int r0 = m * 16 + g * 4;
            float4 M = *reinterpret_cast<const float4*>(maskp + r0);
            f32x4 v = acc[m][c];
            p = fmaf(M.x, fmaxf(v[0] + bb, 0.f), p);
            p = fmaf(M.y, fmaxf(v[1] + bb, 0.f), p);
            p = fmaf(M.z, fmaxf(v[2] + bb, 0.f), p);
            p = fmaf(M.w, fmaxf(v[3] + bb, 0.f), p);
        }
        p += __shfl_xor(p, 16);
        p += __shfl_xor(p, 32);           // all lanes now hold pooled[col]
        float2 mw = *reinterpret_cast<const float2*>(muW + col * 2);
        float2 lw = *reinterpret_cast<const float2*>(lsW + col * 2);
        m0 = fmaf(p, mw.x, m0);
        m1 = fmaf(p, mw.y, m1);
        s0 = fmaf(p, lw.x, s0);
        s1 = fmaf(p, lw.y, s1);
    }
    // reduce over the 16 ln-lanes (g-copies are duplicates; use g==0 only)
#pragma unroll
    for (int off = 1; off < 16; off <<= 1) {
        m0 += __shfl_xor(m0, off);
        m1 += __shfl_xor(m1, off);
        s0 += __shfl_xor(s0, off);
        s1 += __shfl_xor(s1, off);
    }
    if (l == 0) {
        atomicAdd(&accv[b * 4 + 0], m0);
        atomicAdd(&accv[b * 4 + 1], m1);
        atomicAdd(&accv[b * 4 + 2], s0);
        atomicAdd(&accv[b * 4 + 3], s1);
    }
}

// Kernel 3 (2 blocks): Gaussian head, one thread per batch.
__global__ __launch_bounds__(256) void head_kernel(
    const float* __restrict__ accv, const float* __restrict__ eps,
    const float* __restrict__ mub,  const float* __restrict__ lsb,
    float* __restrict__ out)
{
    const int b = blockIdx.x * 256 + threadIdx.x;
    float4 a4 = *reinterpret_cast<const float4*>(accv + b * 4);
    float mu0 = a4.x + mub[0], mu1 = a4.y + mub[1];
    float ls0 = fminf(fmaxf(a4.z + lsb[0], -20.f), 2.f);
    float ls1 = fminf(fmaxf(a4.w + lsb[1], -20.f), 2.f);
    float e0 = eps[b * 2 + 0], e1 = eps[b * 2 + 1];
    float a0 = fmaf(expf(ls0), e0, mu0);
    float a1 = fmaf(expf(ls1), e1, mu1);
    float logp = -0.5f * (e0 * e0 + e1 * e1) - (ls0 + ls1) - 1.8378770664093453f;
    float x0 = -2.f * a0, x1 = -2.f * a1;
    float sp0 = fmaxf(x0, 0.f) + log1pf(expf(-fabsf(x0)));
    float sp1 = fmaxf(x1, 0.f) + log1pf(expf(-fabsf(x1)));
    logp -= 2.f * (0.6931471805599453f - a0 - sp0);
    logp -= 2.f * (0.6931471805599453f - a1 - sp1);
    out[b * 2 + 0] = tanhf(a0);
    out[b * 2 + 1] = tanhf(a1);
    out[1024 + b] = logp;
}

extern "C" void kernel_launch(void* const* d_in, const int* in_sizes, int n_in,
                              void* d_out, int out_size, void* d_ws, size_t ws_size,
                              hipStream_t stream) {
    const float* obs  = (const float*)d_in[0];
    const float* obst = (const float*)d_in[1];
    const float* eps  = (const float*)d_in[2];
    const float* W1   = (const float*)d_in[3];
    const float* b1   = (const float*)d_in[4];
    const float* W2   = (const float*)d_in[5];
    const float* b2   = (const float*)d_in[6];
    const float* muW  = (const float*)d_in[7];
    const float* mub  = (const float*)d_in[8];
    const float* lsW  = (const float*)d_in[9];
    const float* lsb  = (const float*)d_in[10];
    float* out = (float*)d_out;

    char* ws = (char*)d_ws;
    unsigned short* W2p = (unsigned short*)ws;
    unsigned short* A1p = (unsigned short*)(ws + A1P_OFF);
    float* accv         = (float*)(ws + ACCV_OFF);

    prep_kernel<<<37, 256, 0, stream>>>(W2, W1, W2p, A1p, accv);
    actor_kernel<<<2048, 256, 0, stream>>>(obs, obst, W1, b1, b2, W2p, A1p,
                                           muW, lsW, accv);
    head_kernel<<<2, 256, 0, stream>>>(accv, eps, mub, lsb, out);
}

// Round 6
// 37.000 us; speedup vs baseline: 14.0121x; 1.2251x over previous
//
#include <hip/hip_runtime.h>
#include <math.h>

typedef __attribute__((ext_vector_type(8))) short short8;
typedef __attribute__((ext_vector_type(4))) float f32x4;

__device__ __forceinline__ unsigned short f2bf(float x) {
    unsigned u = __float_as_uint(x);
    u += 0x7FFFu + ((u >> 16) & 1u);   // round-to-nearest-even
    return (unsigned short)(u >> 16);
}

#define A1P_OFF 131072

// Kernel 1 (36 blocks): W2p B-fragments + A1p A-fragments.
__global__ __launch_bounds__(256) void prep_kernel(const float* __restrict__ W2,
                                                   const float* __restrict__ W1,
                                                   unsigned short* __restrict__ W2p,
                                                   unsigned short* __restrict__ A1p) {
    const int t = threadIdx.x;
    const int blk = blockIdx.x;
    if (blk < 32) {
        // W2p: frag f=(kt*16+ct)*64+l, elem j = W2[kt*32+(l>>4)*8+j][ct*16+(l&15)]
        int f = blk * 256 + t;
        int l = f & 63, ct = (f >> 6) & 15, kt = f >> 10;
        int col = ct * 16 + (l & 15);
        int krow = kt * 32 + ((l >> 4) * 8);
        short8 v;
#pragma unroll
        for (int j = 0; j < 8; ++j) v[j] = (short)f2bf(W2[(krow + j) * 256 + col]);
        *reinterpret_cast<short8*>(W2p + (size_t)f * 8) = v;
    } else {
        // A1p: W1obst^T A-fragments (M=j, K=32, only k<4 nonzero)
        int f = (blk - 32) * 256 + t;   // 0..1023
        int l = f & 63, jt = f >> 6;
        int j = jt * 16 + (l & 15);
        short8 v;
#pragma unroll
        for (int jj = 0; jj < 8; ++jj) {
            int k = (l >> 4) * 8 + jj;
            v[jj] = (k < 4) ? (short)f2bf(W1[(15 + k) * 256 + j]) : (short)0;
        }
        *reinterpret_cast<short8*>(A1p + (size_t)f * 8) = v;
    }
}

// Kernel 2 (512 blocks x 512 thr): one block per batch. 4 row-slices of 64 through
// 32 KB LDS; W2 B-frags register-cached; fused masked pool + head; 3 stores/block.
__global__ __launch_bounds__(512, 2) void actor_kernel(
    const float* __restrict__ obs,  const float* __restrict__ obst,
    const float* __restrict__ W1,   const float* __restrict__ b1,
    const float* __restrict__ b2,   const unsigned short* __restrict__ W2p,
    const unsigned short* __restrict__ A1p,
    const float* __restrict__ muW,  const float* __restrict__ lsW,
    const float* __restrict__ mub,  const float* __restrict__ lsb,
    const float* __restrict__ eps,  float* __restrict__ out)
{
    __shared__ __align__(16) short sA[4 * 64 * 64];   // 4 pages x (64 rows x 64 k), 32 KB
    __shared__ float sVeh[256];
    __shared__ float sRed[8][4];

    const int b = blockIdx.x;
    const int t = threadIdx.x;
    const int l = t & 63;
    const int w = t >> 6;          // wave: output cols [w*32, w*32+32)
    const int g = l >> 4;
    const int ln = l & 15;

    // per-batch bias vector veh@W1[:15]+b1
    if (t < 256) {
        float a = b1[t];
#pragma unroll
        for (int i = 0; i < 15; ++i) a = fmaf(obs[b * 15 + i], W1[i * 256 + t], a);
        sVeh[t] = a;
    }

    // register-cached layer-2 B-fragments (16 frags = this wave's 32 cols x all K)
    short8 bfr[8][2];
#pragma unroll
    for (int kt = 0; kt < 8; ++kt)
#pragma unroll
        for (int c = 0; c < 2; ++c)
            bfr[kt][c] = *reinterpret_cast<const short8*>(
                W2p + (size_t)(((kt * 16 + (w * 2 + c)) * 64 + l) * 8));

    // layer-1 A-fragments for this wave's 2 j-tiles
    short8 a1[2];
#pragma unroll
    for (int ji = 0; ji < 2; ++ji)
        a1[ji] = *reinterpret_cast<const short8*>(
            A1p + (size_t)(((w * 2 + ji) * 64 + l) * 8));

    // loop-invariant pooling weights for this lane's 2 cols
    float bb[2]; float2 mwv[2], lwv[2];
#pragma unroll
    for (int c = 0; c < 2; ++c) {
        int col = w * 32 + c * 16 + ln;
        bb[c] = b2[col];
        mwv[c] = *reinterpret_cast<const float2*>(muW + col * 2);
        lwv[c] = *reinterpret_cast<const float2*>(lsW + col * 2);
    }

    const float* ob = obst + b * 1280;
    const float* maskbase = ob + 1024;

    // layer-1 B-fragments (obstacle rows, K=4 in low k-slots) for one 64-row slice
    short8 bf1[4];
    auto loadB1 = [&](int q) {
#pragma unroll
        for (int nt = 0; nt < 4; ++nt) {
            short8 v = {0, 0, 0, 0, 0, 0, 0, 0};
            if (l < 16) {
#pragma unroll
                for (int jj = 0; jj < 4; ++jj)
                    v[jj] = (short)f2bf(ob[jj * 256 + q * 64 + nt * 16 + l]);
            }
            bf1[nt] = v;
        }
    };
    loadB1(0);

    f32x4 acc[4][2];
#pragma unroll
    for (int m = 0; m < 4; ++m)
#pragma unroll
        for (int c = 0; c < 2; ++c) acc[m][c] = (f32x4){0.f, 0.f, 0.f, 0.f};
    float m0 = 0.f, m1 = 0.f, s0 = 0.f, s1 = 0.f;

    __syncthreads();   // sVeh ready

    for (int q = 0; q < 4; ++q) {
        // ---- layer 1: this wave's 2 j-tiles x 4 n-tiles -> LDS ----
#pragma unroll
        for (int ji = 0; ji < 2; ++ji) {
            int jt = w * 2 + ji;
            int j0 = jt * 16 + g * 4;
            f32x4 bias = *reinterpret_cast<const f32x4*>(&sVeh[j0]);
            unsigned page = (unsigned)(j0 >> 6) * 8192;
            unsigned jbyte = (unsigned)((j0 & 63) * 2);
#pragma unroll
            for (int nt = 0; nt < 4; ++nt) {
                f32x4 d = (f32x4){0.f, 0.f, 0.f, 0.f};
                d = __builtin_amdgcn_mfma_f32_16x16x32_bf16(a1[ji], bf1[nt], d, 0, 0, 0);
                int n = nt * 16 + ln;
                unsigned p0 = (unsigned)f2bf(fmaxf(d[0] + bias[0], 0.f));
                unsigned p1 = (unsigned)f2bf(fmaxf(d[1] + bias[1], 0.f));
                unsigned p2 = (unsigned)f2bf(fmaxf(d[2] + bias[2], 0.f));
                unsigned p3 = (unsigned)f2bf(fmaxf(d[3] + bias[3], 0.f));
                uint2 u;
                u.x = p0 | (p1 << 16);
                u.y = p2 | (p3 << 16);
                unsigned off = page + (unsigned)(n * 128) + (jbyte ^ ((unsigned)((n & 7) << 4)));
                *reinterpret_cast<uint2*>((char*)sA + off) = u;
            }
        }
        if (q < 3) loadB1(q + 1);   // prefetch next slice's obstacle frags
        __syncthreads();            // h1 slice ready

        // ---- layer 2: full K, B from registers, A from LDS ----
#pragma unroll
        for (int kt = 0; kt < 8; ++kt) {
            unsigned page = (unsigned)(kt >> 1) * 8192;
            unsigned kbyte = (unsigned)((kt & 1) * 64 + g * 16);
#pragma unroll
            for (int m = 0; m < 4; ++m) {
                int n = m * 16 + ln;
                unsigned off = page + (unsigned)(n * 128) + (kbyte ^ ((unsigned)((n & 7) << 4)));
                short8 afr = *reinterpret_cast<const short8*>((const char*)sA + off);
#pragma unroll
                for (int c = 0; c < 2; ++c)
                    acc[m][c] = __builtin_amdgcn_mfma_f32_16x16x32_bf16(afr, bfr[kt][c], acc[m][c], 0, 0, 0);
            }
        }

        // ---- masked pool of this slice, fused with muW/lsW dot; reset acc ----
        const float* maskp = maskbase + q * 64;
#pragma unroll
        for (int c = 0; c < 2; ++c) {
            float p = 0.f;
#pragma unroll
            for (int m = 0; m < 4; ++m) {
                float4 M = *reinterpret_cast<const float4*>(maskp + m * 16 + g * 4);
                f32x4 v = acc[m][c];
                p = fmaf(M.x, fmaxf(v[0] + bb[c], 0.f), p);
                p = fmaf(M.y, fmaxf(v[1] + bb[c], 0.f), p);
                p = fmaf(M.z, fmaxf(v[2] + bb[c], 0.f), p);
                p = fmaf(M.w, fmaxf(v[3] + bb[c], 0.f), p);
                acc[m][c] = (f32x4){0.f, 0.f, 0.f, 0.f};
            }
            p += __shfl_xor(p, 16);
            p += __shfl_xor(p, 32);          // all lanes: pooled partial for col
            m0 = fmaf(p, mwv[c].x, m0);
            m1 = fmaf(p, mwv[c].y, m1);
            s0 = fmaf(p, lwv[c].x, s0);
            s1 = fmaf(p, lwv[c].y, s1);
        }
        if (q < 3) __syncthreads();          // LDS reuse guard
    }

    // ---- block-level reduction + head ----
#pragma unroll
    for (int off = 1; off < 16; off <<= 1) {
        m0 += __shfl_xor(m0, off);
        m1 += __shfl_xor(m1, off);
        s0 += __shfl_xor(s0, off);
        s1 += __shfl_xor(s1, off);
    }
    if (l == 0) { sRed[w][0] = m0; sRed[w][1] = m1; sRed[w][2] = s0; sRed[w][3] = s1; }
    __syncthreads();
    if (t == 0) {
        float M0 = 0.f, M1 = 0.f, S0 = 0.f, S1 = 0.f;
#pragma unroll
        for (int ww = 0; ww < 8; ++ww) {
            M0 += sRed[ww][0]; M1 += sRed[ww][1];
            S0 += sRed[ww][2]; S1 += sRed[ww][3];
        }
        float mu0 = M0 + mub[0], mu1 = M1 + mub[1];
        float ls0 = fminf(fmaxf(S0 + lsb[0], -20.f), 2.f);
        float ls1 = fminf(fmaxf(S1 + lsb[1], -20.f), 2.f);
        float e0 = eps[b * 2 + 0], e1 = eps[b * 2 + 1];
        float a0 = fmaf(expf(ls0), e0, mu0);
        float a1v = fmaf(expf(ls1), e1, mu1);
        float logp = -0.5f * (e0 * e0 + e1 * e1) - (ls0 + ls1) - 1.8378770664093453f;
        float x0 = -2.f * a0, x1 = -2.f * a1v;
        float sp0 = fmaxf(x0, 0.f) + log1pf(expf(-fabsf(x0)));
        float sp1 = fmaxf(x1, 0.f) + log1pf(expf(-fabsf(x1)));
        logp -= 2.f * (0.6931471805599453f - a0 - sp0);
        logp -= 2.f * (0.6931471805599453f - a1v - sp1);
        out[b * 2 + 0] = tanhf(a0);
        out[b * 2 + 1] = tanhf(a1v);
        out[1024 + b] = logp;
    }
}

extern "C" void kernel_launch(void* const* d_in, const int* in_sizes, int n_in,
                              void* d_out, int out_size, void* d_ws, size_t ws_size,
                              hipStream_t stream) {
    const float* obs  = (const float*)d_in[0];
    const float* obst = (const float*)d_in[1];
    const float* eps  = (const float*)d_in[2];
    const float* W1   = (const float*)d_in[3];
    const float* b1   = (const float*)d_in[4];
    const float* W2   = (const float*)d_in[5];
    const float* b2   = (const float*)d_in[6];
    const float* muW  = (const float*)d_in[7];
    const float* mub  = (const float*)d_in[8];
    const float* lsW  = (const float*)d_in[9];
    const float* lsb  = (const float*)d_in[10];
    float* out = (float*)d_out;

    char* ws = (char*)d_ws;
    unsigned short* W2p = (unsigned short*)ws;
    unsigned short* A1p = (unsigned short*)(ws + A1P_OFF);

    prep_kernel<<<36, 256, 0, stream>>>(W2, W1, W2p, A1p);
    actor_kernel<<<512, 512, 0, stream>>>(obs, obst, W1, b1, b2, W2p, A1p,
                                          muW, lsW, mub, lsb, eps, out);
}